// Round 7
// baseline (72.271 us; speedup 1.0000x reference)
//
#include <hip/hip_runtime.h>
#include <cstddef>

typedef __attribute__((ext_vector_type(8))) short short8v;
typedef __attribute__((ext_vector_type(4))) short short4v;
typedef __attribute__((ext_vector_type(4))) float f32x4;

__device__ __forceinline__ unsigned short f2bf(float f) {
    unsigned u = __float_as_uint(f);
    u = (u + 0x7FFFu + ((u >> 16) & 1u)) >> 16;
    return (unsigned short)u;
}

// ---- prep (verified in R4/R6): W[o][d][e][w] fp32 -> Wb frag-stream bf16 ----
// Wb[(g*64+f)*36864 + ks*2048 + nt*512 + lane*8 + j]
//   = bf16( W[o = g*64+nt*16+(lane&15), d = (lane>>4)*8+j, e = 2f+ks/9, w = ks%9] )
__global__ __launch_bounds__(256) void prep_w(const float* __restrict__ w,
                                              unsigned short* __restrict__ wb)
{
    const int g  = blockIdx.x >> 6;
    const int f  = blockIdx.x & 63;
    const int e0 = 2 * f;
    const int tid = threadIdx.x;
    __shared__ unsigned short ls[64 * 580];   // pitch 580 breaks power-of-2 banks

    #pragma unroll 4
    for (int i = 0; i < 72; ++i) {
        int fl  = tid + i * 256;           // (o_l,d) x 9 float2
        int od  = fl / 9;
        int f2i = fl - od * 9;
        int o_l = od >> 5;
        int d   = od & 31;
        const float2 v = *reinterpret_cast<const float2*>(
            &w[(size_t)((g * 64 + o_l) * 32 + d) * 1152 + e0 * 9 + f2i * 2]);
        ushort2 hh; hh.x = f2bf(v.x); hh.y = f2bf(v.y);
        *reinterpret_cast<ushort2*>(&ls[o_l * 580 + d * 18 + f2i * 2]) = hh;
    }
    __syncthreads();

    unsigned short* wo = wb + (size_t)(g * 64 + f) * 36864;
    #pragma unroll 2
    for (int i = 0; i < 18; ++i) {
        int oc   = tid + i * 256;          // (ks, nt, lane)
        int ks   = oc >> 8;
        int nt   = (oc >> 6) & 3;
        int lane = oc & 63;
        int li = lane & 15, hi = lane >> 4;
        int ec = (ks >= 9) ? 1 : 0;
        int w9 = ks - 9 * ec;
        int o_l = nt * 16 + li;
        short8v vv;
        #pragma unroll
        for (int j = 0; j < 8; ++j)
            vv[j] = (short)ls[o_l * 580 + (hi * 8 + j) * 18 + ec * 9 + w9];
        *reinterpret_cast<short8v*>(&wo[(size_t)oc * 8]) = vv;
    }
}

// ---- main: block = (b,g,f), 4 waves of 64n x 32t (acc 4x2). x in LDS (only),
//      A from global frag-stream via depth-2 register ring. ONE barrier/block.
__global__ __launch_bounds__(256, 4) void lconv_mfma(const float* __restrict__ x,
                                                     const unsigned short* __restrict__ wb,
                                                     float* __restrict__ out)
{
    // XCD-chunked swizzle: the 8 b-blocks sharing one (g,f) weight slab -> same XCD
    int bid = blockIdx.x;                       // 0..2047
    int c   = (bid & 7) * 256 + (bid >> 3);
    const int b = c & 7;
    const int f = (c >> 3) & 63;
    const int g = c >> 9;
    const int e0 = 2 * f;

    const int tid  = threadIdx.x;
    const int lane = tid & 63;
    const int th   = tid >> 6;      // wave -> t-quarter
    const int li   = lane & 15;
    const int hi   = lane >> 4;

    // xs[e][tp][d], pitch 40 shorts (odd-quad stride -> uniform read banks)
    __shared__ __align__(16) unsigned short xs[2 * 136 * 40];   // 21760 B

    // ---- stage x (both e): column loads (coalesced over t), b64 LDS writes ----
    {
        const int t = tid & 127;
        const int e = tid >> 7;
        const float* xp0 = &x[((size_t)(b * 128 + g * 32) * 128 + (e0 + e)) * 128 + t];
        #pragma unroll
        for (int dq = 0; dq < 8; ++dq) {
            const float* xp = xp0 + (size_t)dq * 4 * 16384;
            float v0 = xp[0];
            float v1 = xp[16384];
            float v2 = xp[32768];
            float v3 = xp[49152];
            short4v hq;
            hq[0] = (short)f2bf(v0); hq[1] = (short)f2bf(v1);
            hq[2] = (short)f2bf(v2); hq[3] = (short)f2bf(v3);
            *reinterpret_cast<short4v*>(&xs[(e * 136 + t + 4) * 40 + dq * 4]) = hq;
        }
        // zero pads: tp in {0..3, 132..135}, both e, all d
        if (tid < 128) {
            int ez = tid >> 6;
            int r  = (tid >> 3) & 7;
            int dq = tid & 7;
            int tp = (r < 4) ? r : (128 + r);
            short4v zz = {0, 0, 0, 0};
            *reinterpret_cast<short4v*>(&xs[(ez * 136 + tp) * 40 + dq * 4]) = zz;
        }
    }
    __syncthreads();                 // the only barrier in the block

    const unsigned short* wslab = wb + (size_t)(g * 64 + f) * 36864;

    f32x4 acc[4][2];
    #pragma unroll
    for (int nt = 0; nt < 4; ++nt)
        #pragma unroll
        for (int tt = 0; tt < 2; ++tt)
            acc[nt][tt] = (f32x4){0.f, 0.f, 0.f, 0.f};

    // A-frag register ring, 2 ks ahead (fully unrolled -> static indices)
    short8v A[3][4];
    #pragma unroll
    for (int p = 0; p < 2; ++p)
        #pragma unroll
        for (int nt = 0; nt < 4; ++nt)
            A[p][nt] = *reinterpret_cast<const short8v*>(
                &wslab[(size_t)(p * 4 + nt) * 512 + lane * 8]);

    #pragma unroll
    for (int ks = 0; ks < 18; ++ks) {
        const int cur = ks % 3;
        if (ks < 16) {
            const int ld = (ks + 2) % 3;
            #pragma unroll
            for (int nt = 0; nt < 4; ++nt)
                A[ld][nt] = *reinterpret_cast<const short8v*>(
                    &wslab[(size_t)((ks + 2) * 4 + nt) * 512 + lane * 8]);
        }
        const int ec = (ks >= 9) ? 1 : 0;
        const int w9 = ks - 9 * ec;

        short8v Bf[2];
        #pragma unroll
        for (int tt = 0; tt < 2; ++tt) {
            int tp = th * 32 + tt * 16 + li + w9;
            Bf[tt] = *reinterpret_cast<const short8v*>(
                &xs[(ec * 136 + tp) * 40 + hi * 8]);
        }

        #pragma unroll
        for (int nt = 0; nt < 4; ++nt)
            #pragma unroll
            for (int tt = 0; tt < 2; ++tt)
                acc[nt][tt] = __builtin_amdgcn_mfma_f32_16x16x32_bf16(
                    A[cur][nt], Bf[tt], acc[nt][tt], 0, 0, 0);
    }

    // ---- epilogue: LeakyReLU + store (C: col=lane&15 -> t, row=(lane>>4)*4+j -> n) ----
    #pragma unroll
    for (int nt = 0; nt < 4; ++nt) {
        #pragma unroll
        for (int tt = 0; tt < 2; ++tt) {
            #pragma unroll
            for (int j = 0; j < 4; ++j) {
                float v = acc[nt][tt][j];
                v = (v >= 0.f) ? v : 0.01f * v;
                int n  = nt * 16 + hi * 4 + j;
                int tc = th * 32 + tt * 16 + li;
                out[(((size_t)(b * 256 + g * 64 + n)) * 64 + f) * 128 + tc] = v;
            }
        }
    }
}

extern "C" void kernel_launch(void* const* d_in, const int* in_sizes, int n_in,
                              void* d_out, int out_size, void* d_ws, size_t ws_size,
                              hipStream_t stream)
{
    const float* x = (const float*)d_in[0];           // (8,128,128,128) fp32
    const float* w = (const float*)d_in[1];           // (256,32,128,9) fp32
    float* out = (float*)d_out;                       // (8,256,64,128) fp32
    unsigned short* wb = (unsigned short*)d_ws;       // 4*64*36864 bf16 = 18.9 MB

    hipLaunchKernelGGL(prep_w, dim3(256), dim3(256), 0, stream, w, wb);
    hipLaunchKernelGGL(lconv_mfma, dim3(2048), dim3(256), 0, stream, x, wb, out);
}

// Round 8
// 61.643 us; speedup vs baseline: 1.1724x; 1.1724x over previous
//
#include <hip/hip_runtime.h>
#include <cstddef>

typedef __attribute__((ext_vector_type(8))) short short8v;
typedef __attribute__((ext_vector_type(4))) short short4v;
typedef __attribute__((ext_vector_type(4))) float f32x4;

__device__ __forceinline__ unsigned short f2bf(float f) {
    unsigned u = __float_as_uint(f);
    u = (u + 0x7FFFu + ((u >> 16) & 1u)) >> 16;
    return (unsigned short)u;
}

// ---- prep: W[o][d][e][w] fp32 -> Wb frag-stream bf16, grouped by (e, K-half) ----
// per (g,f) slab of 36864 shorts:
//   off(e,w9,nt,lane) = e*18432 + (w9<5 ? (w9*4+nt)*512 : 10240+((w9-5)*4+nt)*512) + lane*8
//   value = bf16( W[o = g*64+nt*16+(lane&15), d = (lane>>4)*8+j, e = 2f+e, w = w9] )
__global__ __launch_bounds__(256) void prep_w(const float* __restrict__ w,
                                              unsigned short* __restrict__ wb)
{
    const int g  = blockIdx.x >> 6;
    const int f  = blockIdx.x & 63;
    const int e0 = 2 * f;
    const int tid = threadIdx.x;
    __shared__ unsigned short ls[64 * 580];   // pitch 580 breaks power-of-2 banks

    #pragma unroll 4
    for (int i = 0; i < 72; ++i) {
        int fl  = tid + i * 256;           // (o_l,d) x 9 float2
        int od  = fl / 9;
        int f2i = fl - od * 9;
        int o_l = od >> 5;
        int d   = od & 31;
        const float2 v = *reinterpret_cast<const float2*>(
            &w[(size_t)((g * 64 + o_l) * 32 + d) * 1152 + e0 * 9 + f2i * 2]);
        ushort2 hh; hh.x = f2bf(v.x); hh.y = f2bf(v.y);
        *reinterpret_cast<ushort2*>(&ls[o_l * 580 + d * 18 + f2i * 2]) = hh;
    }
    __syncthreads();

    unsigned short* wo = wb + (size_t)(g * 64 + f) * 36864;
    #pragma unroll 2
    for (int i = 0; i < 18; ++i) {
        int oc   = tid + i * 256;          // (ks, nt, lane)
        int ks   = oc >> 8;
        int nt   = (oc >> 6) & 3;
        int lane = oc & 63;
        int li = lane & 15, hi = lane >> 4;
        int e  = (ks >= 9) ? 1 : 0;
        int w9 = ks - 9 * e;
        int o_l = nt * 16 + li;
        short8v vv;
        #pragma unroll
        for (int j = 0; j < 8; ++j)
            vv[j] = (short)ls[o_l * 580 + (hi * 8 + j) * 18 + e * 9 + w9];
        int half = (w9 < 5) ? 0 : 1;
        int w9l  = w9 - 5 * half;
        size_t off = (size_t)e * 18432 + half * 10240 + (w9l * 4 + nt) * 512 + lane * 8;
        *reinterpret_cast<short8v*>(&wo[off]) = vv;
    }
}

// ---- main: block = (bp,g,f): 2 batches x 64n x 128t; 4 waves (bl,th) 64x64.
// LDS = xs (21.8 KB, per-e) + As (20.5 KB, per-(e,half)) = 42.2 KB -> 3 blocks/CU.
__global__ __launch_bounds__(256, 3) void lconv_mfma(const float* __restrict__ x,
                                                     const unsigned short* __restrict__ wb,
                                                     float* __restrict__ out)
{
    int bid = blockIdx.x;                       // 0..1023
    int lid = (bid & 7) * 128 + (bid >> 3);     // XCD-chunked swizzle
    const int bp = lid & 3;
    const int f  = (lid >> 2) & 63;
    const int g  = lid >> 8;
    const int e0 = 2 * f;

    const int tid  = threadIdx.x;
    const int lane = tid & 63;
    const int wv   = tid >> 6;
    const int bl   = wv & 1;        // batch within staged pair
    const int th   = wv >> 1;       // t-half
    const int li   = lane & 15;
    const int hi   = lane >> 4;
    const int t    = tid & 127;     // staging lane -> t
    const int z    = tid >> 7;      // staging batch slot

    __shared__ __align__(16) unsigned short xs[2 * 136 * 40];   // 21760 B
    __shared__ __align__(16) unsigned short As[10240];          // 20480 B (42240 total)

    // zero pads once: tp in {0..3, 132..135}, both slots, all d (never overwritten)
    if (tid < 128) {
        int blz = tid >> 6;
        int r   = (tid >> 3) & 7;
        int dq  = tid & 7;
        int tp  = (r < 4) ? r : (128 + r);
        short4v zz = {0, 0, 0, 0};
        *reinterpret_cast<short4v*>(&xs[(blz * 136 + tp) * 40 + dq * 4]) = zz;
    }

    const unsigned short* wA = wb + (size_t)(g * 64 + f) * 36864;

    float   xr[32];
    short8v ar[5];

    f32x4 acc[4][4];
    #pragma unroll
    for (int nt = 0; nt < 4; ++nt)
        #pragma unroll
        for (int tt = 0; tt < 4; ++tt)
            acc[nt][tt] = (f32x4){0.f, 0.f, 0.f, 0.f};

    auto issueX = [&](int ec) {
        const int e  = e0 + ec;
        const int b0 = bp * 2 + z;
        const float* xp0 = &x[((size_t)(b0 * 128 + g * 32) * 128 + e) * 128 + t];
        #pragma unroll
        for (int dq = 0; dq < 8; ++dq) {
            const float* xp = xp0 + (size_t)dq * 4 * 16384;
            xr[dq * 4 + 0] = xp[0];
            xr[dq * 4 + 1] = xp[16384];
            xr[dq * 4 + 2] = xp[32768];
            xr[dq * 4 + 3] = xp[49152];
        }
    };
    auto lwriteX = [&]() {
        #pragma unroll
        for (int dq = 0; dq < 8; ++dq) {
            short4v hq;
            hq[0] = (short)f2bf(xr[dq * 4 + 0]);
            hq[1] = (short)f2bf(xr[dq * 4 + 1]);
            hq[2] = (short)f2bf(xr[dq * 4 + 2]);
            hq[3] = (short)f2bf(xr[dq * 4 + 3]);
            *reinterpret_cast<short4v*>(&xs[(z * 136 + t + 4) * 40 + dq * 4]) = hq;
        }
    };
    auto issueA = [&](int ec, int h) {
        const short8v* src = reinterpret_cast<const short8v*>(
            wA + (size_t)ec * 18432 + h * 10240);
        const int cnt = h ? 4 : 5;
        #pragma unroll
        for (int i = 0; i < 5; ++i)
            if (i < cnt) ar[i] = src[tid + i * 256];
    };
    auto lwriteA = [&](int h) {
        short8v* dst = reinterpret_cast<short8v*>(As);
        const int cnt = h ? 4 : 5;
        #pragma unroll
        for (int i = 0; i < 5; ++i)
            if (i < cnt) dst[tid + i * 256] = ar[i];
    };
    auto compute = [&](int h) {
        const int cnt = h ? 4 : 5;
        const int wb9 = h ? 5 : 0;
        #pragma unroll
        for (int w9l = 0; w9l < 5; ++w9l) {
            if (w9l >= cnt) break;
            short8v Af[4], Bf[4];
            #pragma unroll
            for (int nt = 0; nt < 4; ++nt)          // lane-linear: conflict-free
                Af[nt] = *reinterpret_cast<const short8v*>(
                    &As[(w9l * 4 + nt) * 512 + lane * 8]);
            #pragma unroll
            for (int tt = 0; tt < 4; ++tt) {
                int tp = th * 64 + tt * 16 + li + wb9 + w9l;
                Bf[tt] = *reinterpret_cast<const short8v*>(
                    &xs[(bl * 136 + tp) * 40 + hi * 8]);
            }
            __builtin_amdgcn_s_setprio(1);
            #pragma unroll
            for (int nt = 0; nt < 4; ++nt)
                #pragma unroll
                for (int tt = 0; tt < 4; ++tt)
                    acc[nt][tt] = __builtin_amdgcn_mfma_f32_16x16x32_bf16(
                        Af[nt], Bf[tt], acc[nt][tt], 0, 0, 0);
            __builtin_amdgcn_s_setprio(0);
        }
    };

    // ---- pipeline over (ec, half) ----
    issueX(0); issueA(0, 0);
    lwriteX(); lwriteA(0);
    __syncthreads();

    issueA(0, 1);
    compute(0);                       // (e0, h0)
    __syncthreads();
    lwriteA(1);
    __syncthreads();

    issueX(1);
    compute(1);                       // (e0, h1)
    __syncthreads();
    lwriteX();
    issueA(1, 0);
    lwriteA(0);
    __syncthreads();

    issueA(1, 1);
    compute(0);                       // (e1, h0)
    __syncthreads();
    lwriteA(1);
    __syncthreads();

    compute(1);                       // (e1, h1)

    // ---- epilogue: LeakyReLU + store (C: col=lane&15 -> t, row=(lane>>4)*4+j -> n) ----
    const int b = bp * 2 + bl;
    #pragma unroll
    for (int nt = 0; nt < 4; ++nt) {
        #pragma unroll
        for (int tt = 0; tt < 4; ++tt) {
            #pragma unroll
            for (int j = 0; j < 4; ++j) {
                float v = acc[nt][tt][j];
                v = (v >= 0.f) ? v : 0.01f * v;
                int n  = nt * 16 + hi * 4 + j;
                int tc = th * 64 + tt * 16 + li;
                out[(((size_t)(b * 256 + g * 64 + n)) * 64 + f) * 128 + tc] = v;
            }
        }
    }
}

extern "C" void kernel_launch(void* const* d_in, const int* in_sizes, int n_in,
                              void* d_out, int out_size, void* d_ws, size_t ws_size,
                              hipStream_t stream)
{
    const float* x = (const float*)d_in[0];           // (8,128,128,128) fp32
    const float* w = (const float*)d_in[1];           // (256,32,128,9) fp32
    float* out = (float*)d_out;                       // (8,256,64,128) fp32
    unsigned short* wb = (unsigned short*)d_ws;       // 4*64*36864 bf16 = 18.9 MB

    hipLaunchKernelGGL(prep_w, dim3(256), dim3(256), 0, stream, w, wb);
    hipLaunchKernelGGL(lconv_mfma, dim3(1024), dim3(256), 0, stream, x, wb, out);
}

// Round 9
// 54.051 us; speedup vs baseline: 1.3371x; 1.1405x over previous
//
#include <hip/hip_runtime.h>
#include <cstddef>

typedef __attribute__((ext_vector_type(8))) short short8v;
typedef __attribute__((ext_vector_type(4))) short short4v;
typedef __attribute__((ext_vector_type(4))) float f32x4;

__device__ __forceinline__ unsigned short f2bf(float f) {
    unsigned u = __float_as_uint(f);
    u = (u + 0x7FFFu + ((u >> 16) & 1u)) >> 16;
    return (unsigned short)u;
}

// ---- prep: W[o][d][e][w] fp32 -> Wb frag-stream bf16, sliced by (g,f,nh) ----
// Wb[((g*64+f)*2+nh)*18432 + e*9216 + (w9*2+nt2)*512 + lane*8 + j]
//   = bf16( W[o = g*64+nh*32+nt2*16+(lane&15), d = (lane>>4)*8+j, e = 2f+e, w = w9] )
__global__ __launch_bounds__(256) void prep_w(const float* __restrict__ w,
                                              unsigned short* __restrict__ wb)
{
    const int g  = blockIdx.x >> 6;
    const int f  = blockIdx.x & 63;
    const int e0 = 2 * f;
    const int tid = threadIdx.x;
    __shared__ unsigned short ls[64 * 580];   // pitch 580 breaks power-of-2 banks

    #pragma unroll 4
    for (int i = 0; i < 72; ++i) {
        int fl  = tid + i * 256;           // (o_l,d) x 9 float2
        int od  = fl / 9;
        int f2i = fl - od * 9;
        int o_l = od >> 5;
        int d   = od & 31;
        const float2 v = *reinterpret_cast<const float2*>(
            &w[(size_t)((g * 64 + o_l) * 32 + d) * 1152 + e0 * 9 + f2i * 2]);
        ushort2 hh; hh.x = f2bf(v.x); hh.y = f2bf(v.y);
        *reinterpret_cast<ushort2*>(&ls[o_l * 580 + d * 18 + f2i * 2]) = hh;
    }
    __syncthreads();

    unsigned short* wo = wb + (size_t)(g * 64 + f) * 36864;
    #pragma unroll 2
    for (int i = 0; i < 18; ++i) {
        int oc   = tid + i * 256;          // (ks, nt4, lane)
        int ks   = oc >> 8;                // 0..17
        int nt4  = (oc >> 6) & 3;
        int lane = oc & 63;
        int li = lane & 15, hi = lane >> 4;
        int e  = (ks >= 9) ? 1 : 0;
        int w9 = ks - 9 * e;
        int o_l = nt4 * 16 + li;
        short8v vv;
        #pragma unroll
        for (int j = 0; j < 8; ++j)
            vv[j] = (short)ls[o_l * 580 + (hi * 8 + j) * 18 + e * 9 + w9];
        int nh  = nt4 >> 1;
        int nt2 = nt4 & 1;
        size_t off = (size_t)nh * 18432 + e * 9216 + (w9 * 2 + nt2) * 512 + lane * 8;
        *reinterpret_cast<short8v*>(&wo[off]) = vv;
    }
}

// ---- main: block = (g,f,nh): 32 n x 128 t, LOOP over all 8 batches.
// A (36.9 KB) staged ONCE; xs (21.8 KB) re-staged per b with reg-prefetch.
// 58.6 KB LDS -> 2 blocks/CU; grid 512 -> all resident, zero tail.
__global__ __launch_bounds__(256, 2) void lconv_mfma(const float* __restrict__ x,
                                                     const unsigned short* __restrict__ wb,
                                                     float* __restrict__ out)
{
    int bid = blockIdx.x;                       // 0..511
    int lid = (bid & 7) * 64 + (bid >> 3);      // XCD-chunked: n-siblings same XCD
    const int nh = lid & 1;
    const int f  = (lid >> 1) & 63;
    const int g  = lid >> 7;
    const int e0 = 2 * f;

    const int tid  = threadIdx.x;
    const int lane = tid & 63;
    const int th   = tid >> 6;      // wave -> t-quarter
    const int li   = lane & 15;
    const int hi   = lane >> 4;
    const int t    = tid & 127;     // staging lane -> t
    const int ez   = tid >> 7;      // staging e

    __shared__ __align__(16) unsigned short xs[2 * 136 * 40];   // 21760 B
    __shared__ __align__(16) unsigned short As[18432];          // 36864 B (58624 total)

    float   xr[32];
    short8v ar[9];

    auto issueX = [&](int b) {
        const float* xp0 = &x[((size_t)(b * 128 + g * 32) * 128 + (e0 + ez)) * 128 + t];
        #pragma unroll
        for (int dq = 0; dq < 8; ++dq) {
            const float* xp = xp0 + (size_t)dq * 4 * 16384;
            xr[dq * 4 + 0] = xp[0];
            xr[dq * 4 + 1] = xp[16384];
            xr[dq * 4 + 2] = xp[32768];
            xr[dq * 4 + 3] = xp[49152];
        }
    };
    auto lwriteX = [&]() {
        #pragma unroll
        for (int dq = 0; dq < 8; ++dq) {
            short4v hq;
            hq[0] = (short)f2bf(xr[dq * 4 + 0]);
            hq[1] = (short)f2bf(xr[dq * 4 + 1]);
            hq[2] = (short)f2bf(xr[dq * 4 + 2]);
            hq[3] = (short)f2bf(xr[dq * 4 + 3]);
            *reinterpret_cast<short4v*>(&xs[(ez * 136 + t + 4) * 40 + dq * 4]) = hq;
        }
    };

    // ---- prologue: A-slab + x(b=0) + pads, single barrier ----
    {
        const short8v* asrc = reinterpret_cast<const short8v*>(
            wb + (size_t)((g * 64 + f) * 2 + nh) * 18432);
        #pragma unroll
        for (int i = 0; i < 9; ++i) ar[i] = asrc[tid + i * 256];
    }
    issueX(0);
    if (tid < 128) {          // zero pads: tp in {0..3, 132..135}, both e, all d
        int e  = tid >> 6;
        int r  = (tid >> 3) & 7;
        int dq = tid & 7;
        int tp = (r < 4) ? r : (128 + r);
        short4v zz = {0, 0, 0, 0};
        *reinterpret_cast<short4v*>(&xs[(e * 136 + tp) * 40 + dq * 4]) = zz;
    }
    {
        short8v* dst = reinterpret_cast<short8v*>(As);
        #pragma unroll
        for (int i = 0; i < 9; ++i) dst[tid + i * 256] = ar[i];
    }
    lwriteX();
    __syncthreads();

    f32x4 acc[2][2];
    #pragma unroll
    for (int nt = 0; nt < 2; ++nt)
        #pragma unroll
        for (int tt = 0; tt < 2; ++tt)
            acc[nt][tt] = (f32x4){0.f, 0.f, 0.f, 0.f};

    for (int b = 0; b < 8; ++b) {
        if (b < 7) issueX(b + 1);       // drains under compute (T14)

        #pragma unroll
        for (int e = 0; e < 2; ++e) {
            #pragma unroll
            for (int w9 = 0; w9 < 9; ++w9) {
                short8v Af[2], Bf[2];
                #pragma unroll
                for (int nt = 0; nt < 2; ++nt)   // lane-linear: conflict-free
                    Af[nt] = *reinterpret_cast<const short8v*>(
                        &As[e * 9216 + (w9 * 2 + nt) * 512 + lane * 8]);
                #pragma unroll
                for (int tt = 0; tt < 2; ++tt) {
                    int tp = th * 32 + tt * 16 + li + w9;
                    Bf[tt] = *reinterpret_cast<const short8v*>(
                        &xs[(e * 136 + tp) * 40 + hi * 8]);
                }
                __builtin_amdgcn_s_setprio(1);
                #pragma unroll
                for (int nt = 0; nt < 2; ++nt)
                    #pragma unroll
                    for (int tt = 0; tt < 2; ++tt)
                        acc[nt][tt] = __builtin_amdgcn_mfma_f32_16x16x32_bf16(
                            Af[nt], Bf[tt], acc[nt][tt], 0, 0, 0);
                __builtin_amdgcn_s_setprio(0);
            }
        }

        // epilogue for this b: LeakyReLU + store, then reset acc
        #pragma unroll
        for (int nt = 0; nt < 2; ++nt)
            #pragma unroll
            for (int tt = 0; tt < 2; ++tt)
                #pragma unroll
                for (int j = 0; j < 4; ++j) {
                    float v = acc[nt][tt][j];
                    v = (v >= 0.f) ? v : 0.01f * v;
                    int n  = nh * 32 + nt * 16 + hi * 4 + j;
                    int tc = th * 32 + tt * 16 + li;
                    out[(((size_t)(b * 256 + g * 64 + n)) * 64 + f) * 128 + tc] = v;
                    acc[nt][tt][j] = 0.f;
                }

        __syncthreads();                 // all waves done reading xs[b]
        if (b < 7) {
            lwriteX();                   // xr -> xs (b+1)
            __syncthreads();
        }
    }
}

extern "C" void kernel_launch(void* const* d_in, const int* in_sizes, int n_in,
                              void* d_out, int out_size, void* d_ws, size_t ws_size,
                              hipStream_t stream)
{
    const float* x = (const float*)d_in[0];           // (8,128,128,128) fp32
    const float* w = (const float*)d_in[1];           // (256,32,128,9) fp32
    float* out = (float*)d_out;                       // (8,256,64,128) fp32
    unsigned short* wb = (unsigned short*)d_ws;       // 256*2*18432 bf16 = 18.9 MB

    hipLaunchKernelGGL(prep_w, dim3(256), dim3(256), 0, stream, w, wb);
    hipLaunchKernelGGL(lconv_mfma, dim3(512), dim3(256), 0, stream, x, wb, out);
}

// Round 10
// 53.881 us; speedup vs baseline: 1.3413x; 1.0032x over previous
//
#include <hip/hip_runtime.h>
#include <cstddef>

typedef __attribute__((ext_vector_type(8))) short short8v;
typedef __attribute__((ext_vector_type(4))) short short4v;
typedef __attribute__((ext_vector_type(4))) float f32x4;

__device__ __forceinline__ unsigned short f2bf(float f) {
    unsigned u = __float_as_uint(f);
    u = (u + 0x7FFFu + ((u >> 16) & 1u)) >> 16;
    return (unsigned short)u;
}

// ---- prep (verified R4/R6): W[o][d][e][w] fp32 -> Wb frag-stream bf16 ----
// Wb[(g*64+f)*36864 + ks*2048 + nt*512 + lane*8 + j], ks = e*9 + w9
//   = bf16( W[o = g*64+nt*16+(lane&15), d = (lane>>4)*8+j, e = 2f+e, w = w9] )
__global__ __launch_bounds__(256) void prep_w(const float* __restrict__ w,
                                              unsigned short* __restrict__ wb)
{
    const int g  = blockIdx.x >> 6;
    const int f  = blockIdx.x & 63;
    const int e0 = 2 * f;
    const int tid = threadIdx.x;
    __shared__ unsigned short ls[64 * 580];   // pitch 580 breaks power-of-2 banks

    #pragma unroll 4
    for (int i = 0; i < 72; ++i) {
        int fl  = tid + i * 256;           // (o_l,d) x 9 float2
        int od  = fl / 9;
        int f2i = fl - od * 9;
        int o_l = od >> 5;
        int d   = od & 31;
        const float2 v = *reinterpret_cast<const float2*>(
            &w[(size_t)((g * 64 + o_l) * 32 + d) * 1152 + e0 * 9 + f2i * 2]);
        ushort2 hh; hh.x = f2bf(v.x); hh.y = f2bf(v.y);
        *reinterpret_cast<ushort2*>(&ls[o_l * 580 + d * 18 + f2i * 2]) = hh;
    }
    __syncthreads();

    unsigned short* wo = wb + (size_t)(g * 64 + f) * 36864;
    #pragma unroll 2
    for (int i = 0; i < 18; ++i) {
        int oc   = tid + i * 256;          // (ks, nt, lane)
        int ks   = oc >> 8;
        int nt   = (oc >> 6) & 3;
        int lane = oc & 63;
        int li = lane & 15, hi = lane >> 4;
        int e  = (ks >= 9) ? 1 : 0;
        int w9 = ks - 9 * e;
        int o_l = nt * 16 + li;
        short8v vv;
        #pragma unroll
        for (int j = 0; j < 8; ++j)
            vv[j] = (short)ls[o_l * 580 + (hi * 8 + j) * 18 + e * 9 + w9];
        *reinterpret_cast<short8v*>(&wo[(size_t)oc * 8]) = vv;
    }
}

// ---- main: block = (g,f), 256 threads = 4 waves (bl,th), wave tile 64n x 64t.
// Dynamic LDS 117248 B: As (73728 B, full K=576, resident once) +
// xs[e][bl][136][40] (43520 B). Loop over 4 batch-pairs, e-slab interleave
// double-buffers staging; every vmcnt drain is covered by a compute half.
__global__ __launch_bounds__(256, 1) void lconv_mfma(const float* __restrict__ x,
                                                     const unsigned short* __restrict__ wb,
                                                     float* __restrict__ out)
{
    extern __shared__ __align__(16) unsigned short smem[];
    unsigned short* As = smem;            // 36864 shorts
    unsigned short* xs = smem + 36864;    // 21760 shorts: 4 slabs of 5440

    const int g  = blockIdx.x >> 6;
    const int f  = blockIdx.x & 63;
    const int e0 = 2 * f;

    const int tid  = threadIdx.x;
    const int lane = tid & 63;
    const int wv   = tid >> 6;
    const int bl   = wv & 1;        // batch within pair
    const int th   = wv >> 1;       // t-half
    const int li   = lane & 15;
    const int hi   = lane >> 4;
    const int t    = tid & 127;     // staging lane -> t
    const int z    = tid >> 7;      // staging batch slot

    const unsigned short* wslab = wb + (size_t)(g * 64 + f) * 36864;

    // ---- A: async global->LDS, 18 chunks x (4 waves x 1024 B), linear ----
    #pragma unroll
    for (int i = 0; i < 18; ++i) {
        int off = i * 2048 + wv * 512 + lane * 8;
        __builtin_amdgcn_global_load_lds(
            (const __attribute__((address_space(1))) void*)(wslab + off),
            (__attribute__((address_space(3))) void*)(As + i * 2048 + wv * 512),
            16, 0, 0);
    }

    float xr[32];
    auto issueX = [&](int p, int e) {       // load x(b = p*2+z, e0+e), all 32 d at t
        const int b = p * 2 + z;
        const float* xp0 = &x[((size_t)(b * 128 + g * 32) * 128 + (e0 + e)) * 128 + t];
        #pragma unroll
        for (int d = 0; d < 32; ++d)
            xr[d] = xp0[(size_t)d * 16384];
    };
    auto lwriteX = [&](int e) {
        unsigned short* base = xs + (e * 2 + z) * 5440;
        #pragma unroll
        for (int dq = 0; dq < 8; ++dq) {
            short4v hq;
            hq[0] = (short)f2bf(xr[dq * 4 + 0]);
            hq[1] = (short)f2bf(xr[dq * 4 + 1]);
            hq[2] = (short)f2bf(xr[dq * 4 + 2]);
            hq[3] = (short)f2bf(xr[dq * 4 + 3]);
            *reinterpret_cast<short4v*>(&base[(t + 4) * 40 + dq * 4]) = hq;
        }
    };

    // zero pads: tp in {0..3, 132..135}, all 4 slabs, all d
    {
        int e  = tid >> 7;
        int b2 = (tid >> 6) & 1;
        int r  = (tid >> 3) & 7;
        int dq = tid & 7;
        int tp = (r < 4) ? r : (128 + r);
        short4v zz = {0, 0, 0, 0};
        *reinterpret_cast<short4v*>(&xs[(e * 2 + b2) * 5440 + tp * 40 + dq * 4]) = zz;
    }

    // ---- prologue staging: pair0 both halves + pair1 e0 in flight ----
    issueX(0, 0); lwriteX(0);
    issueX(0, 1); lwriteX(1);
    issueX(1, 0);
    __syncthreads();                  // drains A + all x; everything valid

    f32x4 acc[4][4];
    #pragma unroll
    for (int nt = 0; nt < 4; ++nt)
        #pragma unroll
        for (int tt = 0; tt < 4; ++tt)
            acc[nt][tt] = (f32x4){0.f, 0.f, 0.f, 0.f};

    auto compute = [&](int e) {
        const unsigned short* xb = xs + (e * 2 + bl) * 5440;
        #pragma unroll
        for (int w9 = 0; w9 < 9; ++w9) {
            short8v Af[4], Bf[4];
            #pragma unroll
            for (int nt = 0; nt < 4; ++nt)   // lane-linear: conflict-free
                Af[nt] = *reinterpret_cast<const short8v*>(
                    &As[(e * 9 + w9) * 2048 + nt * 512 + lane * 8]);
            #pragma unroll
            for (int tt = 0; tt < 4; ++tt) {
                int tp = th * 64 + tt * 16 + li + w9;
                Bf[tt] = *reinterpret_cast<const short8v*>(&xb[tp * 40 + hi * 8]);
            }
            __builtin_amdgcn_s_setprio(1);
            #pragma unroll
            for (int nt = 0; nt < 4; ++nt)
                #pragma unroll
                for (int tt = 0; tt < 4; ++tt)
                    acc[nt][tt] = __builtin_amdgcn_mfma_f32_16x16x32_bf16(
                        Af[nt], Bf[tt], acc[nt][tt], 0, 0, 0);
            __builtin_amdgcn_s_setprio(0);
        }
    };

    for (int p = 0; p < 4; ++p) {
        compute(0);                          // reads xs[e0][bl]
        __syncthreads();                     // drains x(p+1,e0) (covered by compute)
        if (p < 3) {
            lwriteX(0);                      // x(p+1,e0) -> slab, regs free
            issueX(p + 1, 1);                // x(p+1,e1) in flight
            __builtin_amdgcn_sched_barrier(0);
        }
        compute(1);                          // reads xs[e1][bl]
        __syncthreads();                     // drains x(p+1,e1) (covered)
        if (p < 3) lwriteX(1);
        if (p < 2) {
            issueX(p + 2, 0);                // x(p+2,e0) in flight
            __builtin_amdgcn_sched_barrier(0);
        }

        // epilogue for this pair: LeakyReLU + store, reset acc
        const int b = p * 2 + bl;
        #pragma unroll
        for (int nt = 0; nt < 4; ++nt)
            #pragma unroll
            for (int tt = 0; tt < 4; ++tt)
                #pragma unroll
                for (int j = 0; j < 4; ++j) {
                    float v = acc[nt][tt][j];
                    v = (v >= 0.f) ? v : 0.01f * v;
                    int n  = nt * 16 + hi * 4 + j;
                    int tc = th * 64 + tt * 16 + li;
                    out[(((size_t)(b * 256 + g * 64 + n)) * 64 + f) * 128 + tc] = v;
                    acc[nt][tt][j] = 0.f;
                }
    }
}

extern "C" void kernel_launch(void* const* d_in, const int* in_sizes, int n_in,
                              void* d_out, int out_size, void* d_ws, size_t ws_size,
                              hipStream_t stream)
{
    const float* x = (const float*)d_in[0];           // (8,128,128,128) fp32
    const float* w = (const float*)d_in[1];           // (256,32,128,9) fp32
    float* out = (float*)d_out;                       // (8,256,64,128) fp32
    unsigned short* wb = (unsigned short*)d_ws;       // 256*36864 bf16 = 18.9 MB

    (void)hipFuncSetAttribute((const void*)lconv_mfma,
                              hipFuncAttributeMaxDynamicSharedMemorySize, 117248);

    hipLaunchKernelGGL(prep_w, dim3(256), dim3(256), 0, stream, w, wb);
    hipLaunchKernelGGL(lconv_mfma, dim3(256), dim3(256), 117248, stream, x, wb, out);
}

// Round 11
// 53.307 us; speedup vs baseline: 1.3557x; 1.0108x over previous
//
#include <hip/hip_runtime.h>
#include <cstddef>

typedef __attribute__((ext_vector_type(8))) short short8v;
typedef __attribute__((ext_vector_type(4))) short short4v;
typedef __attribute__((ext_vector_type(4))) float f32x4;

__device__ __forceinline__ unsigned short f2bf(float f) {
    unsigned u = __float_as_uint(f);
    u = (u + 0x7FFFu + ((u >> 16) & 1u)) >> 16;
    return (unsigned short)u;
}

// ---- prep (verified R4/R6/R10): W[o][d][e][w] fp32 -> Wb frag-stream bf16 ----
// Wb[(g*64+f)*36864 + ks*2048 + nt*512 + lane*8 + j], ks = e*9 + w9
//   = bf16( W[o = g*64+nt*16+(lane&15), d = (lane>>4)*8+j, e = 2f+e, w = w9] )
__global__ __launch_bounds__(256) void prep_w(const float* __restrict__ w,
                                              unsigned short* __restrict__ wb)
{
    const int g  = blockIdx.x >> 6;
    const int f  = blockIdx.x & 63;
    const int e0 = 2 * f;
    const int tid = threadIdx.x;
    __shared__ unsigned short ls[64 * 580];   // pitch 580 breaks power-of-2 banks

    #pragma unroll 4
    for (int i = 0; i < 72; ++i) {
        int fl  = tid + i * 256;           // (o_l,d) x 9 float2
        int od  = fl / 9;
        int f2i = fl - od * 9;
        int o_l = od >> 5;
        int d   = od & 31;
        const float2 v = *reinterpret_cast<const float2*>(
            &w[(size_t)((g * 64 + o_l) * 32 + d) * 1152 + e0 * 9 + f2i * 2]);
        ushort2 hh; hh.x = f2bf(v.x); hh.y = f2bf(v.y);
        *reinterpret_cast<ushort2*>(&ls[o_l * 580 + d * 18 + f2i * 2]) = hh;
    }
    __syncthreads();

    unsigned short* wo = wb + (size_t)(g * 64 + f) * 36864;
    #pragma unroll 2
    for (int i = 0; i < 18; ++i) {
        int oc   = tid + i * 256;          // (ks, nt, lane)
        int ks   = oc >> 8;
        int nt   = (oc >> 6) & 3;
        int lane = oc & 63;
        int li = lane & 15, hi = lane >> 4;
        int e  = (ks >= 9) ? 1 : 0;
        int w9 = ks - 9 * e;
        int o_l = nt * 16 + li;
        short8v vv;
        #pragma unroll
        for (int j = 0; j < 8; ++j)
            vv[j] = (short)ls[o_l * 580 + (hi * 8 + j) * 18 + e * 9 + w9];
        *reinterpret_cast<short8v*>(&wo[(size_t)oc * 8]) = vv;
    }
}

// ---- main: block = (g,f), 4 waves. Each wave owns batches {wv, wv+4} and a
// PRIVATE x slab: staging is within-wave (no barriers). Wave tile 64n x 128t
// (acc 4x8). One __syncthreads total (A-slab readiness). LDS 160768 B.
__global__ __launch_bounds__(256, 1) void lconv_mfma(const float* __restrict__ x,
                                                     const unsigned short* __restrict__ wb,
                                                     float* __restrict__ out)
{
    extern __shared__ __align__(16) unsigned short smem[];
    unsigned short* As = smem;                       // 36864 shorts

    const int g  = blockIdx.x >> 6;
    const int f  = blockIdx.x & 63;
    const int e0 = 2 * f;

    const int tid  = threadIdx.x;
    const int lane = tid & 63;
    const int wv   = tid >> 6;
    const int li   = lane & 15;
    const int hi   = lane >> 4;

    unsigned short* xsw = smem + 36864 + wv * 10880; // private [e][136][40]

    // ---- A: async global->LDS, linear, all 256 threads ----
    const unsigned short* wslab = wb + (size_t)(g * 64 + f) * 36864;
    #pragma unroll
    for (int i = 0; i < 18; ++i) {
        __builtin_amdgcn_global_load_lds(
            (const __attribute__((address_space(1))) void*)(wslab + i * 2048 + tid * 8),
            (__attribute__((address_space(3))) void*)(As + i * 2048 + tid * 8),
            16, 0, 0);
    }

    // ---- zero pads for own slab: tp in {0..3, 132..135}, both e, d 0..39 ----
    #pragma unroll
    for (int it = 0; it < 3; ++it) {
        int u = it * 64 + lane;             // (e, r, dq): 2*8*10 = 160
        if (u < 160) {
            int e  = u / 80;
            int r  = (u % 80) / 10;
            int dq = u % 10;
            int tp = (r < 4) ? r : (128 + r);
            short4v zz = {0, 0, 0, 0};
            *reinterpret_cast<short4v*>(&xsw[e * 5440 + tp * 40 + dq * 4]) = zz;
        }
    }

    float2 fr[32];
    auto issueX = [&](int b, int e) {        // 32 float2: all d at t = 2*lane,+1
        const float* xp0 = &x[((size_t)(b * 128 + g * 32) * 128 + (e0 + e)) * 128 + 2 * lane];
        #pragma unroll
        for (int d = 0; d < 32; ++d)
            fr[d] = *reinterpret_cast<const float2*>(xp0 + (size_t)d * 16384);
    };
    auto lwriteX = [&](int e) {
        unsigned short* base = xsw + e * 5440 + (2 * lane + 4) * 40;
        #pragma unroll
        for (int dq = 0; dq < 8; ++dq) {
            short4v h0, h1;
            #pragma unroll
            for (int j = 0; j < 4; ++j) {
                h0[j] = (short)f2bf(fr[dq * 4 + j].x);
                h1[j] = (short)f2bf(fr[dq * 4 + j].y);
            }
            *reinterpret_cast<short4v*>(&base[dq * 4])      = h0;
            *reinterpret_cast<short4v*>(&base[40 + dq * 4]) = h1;
        }
    };

    // ---- stage own batch b0 = wv (both e) ----
    const int b0 = wv, b1 = wv + 4;
    issueX(b0, 0); lwriteX(0);
    issueX(b0, 1); lwriteX(1);
    __syncthreads();                 // A ready (also drains x stage)

    f32x4 acc[4][8];
    #pragma unroll
    for (int nt = 0; nt < 4; ++nt)
        #pragma unroll
        for (int tt = 0; tt < 8; ++tt)
            acc[nt][tt] = (f32x4){0.f, 0.f, 0.f, 0.f};

    auto compute_half = [&](int e) {
        #pragma unroll
        for (int w9 = 0; w9 < 9; ++w9) {
            short8v Af[4], Bf[8];
            #pragma unroll
            for (int nt = 0; nt < 4; ++nt)   // lane-linear: conflict-free
                Af[nt] = *reinterpret_cast<const short8v*>(
                    &As[(e * 9 + w9) * 2048 + nt * 512 + lane * 8]);
            #pragma unroll
            for (int tt = 0; tt < 8; ++tt) {
                int tp = tt * 16 + li + w9;
                Bf[tt] = *reinterpret_cast<const short8v*>(
                    &xsw[e * 5440 + tp * 40 + hi * 8]);
            }
            __builtin_amdgcn_s_setprio(1);
            #pragma unroll
            for (int nt = 0; nt < 4; ++nt)
                #pragma unroll
                for (int tt = 0; tt < 8; ++tt)
                    acc[nt][tt] = __builtin_amdgcn_mfma_f32_16x16x32_bf16(
                        Af[nt], Bf[tt], acc[nt][tt], 0, 0, 0);
            __builtin_amdgcn_s_setprio(0);
        }
    };

    auto store_b = [&](int b) {
        #pragma unroll
        for (int nt = 0; nt < 4; ++nt)
            #pragma unroll
            for (int tt = 0; tt < 8; ++tt)
                #pragma unroll
                for (int j = 0; j < 4; ++j) {
                    float v = acc[nt][tt][j];
                    v = (v >= 0.f) ? v : 0.01f * v;
                    int n  = nt * 16 + hi * 4 + j;
                    int tc = tt * 16 + li;
                    out[(((size_t)(b * 256 + g * 64 + n)) * 64 + f) * 128 + tc] = v;
                    acc[nt][tt][j] = 0.f;
                }
    };

    // ---- batch b0, overlapping b1 staging (slab-half legality) ----
    issueX(b1, 0);                   // in flight under e0 compute
    compute_half(0);                 // reads slab e0 (b0) -> e0 free
    lwriteX(0);                      // b1 -> slab e0
    issueX(b1, 1);                   // in flight under e1 compute
    compute_half(1);                 // reads slab e1 (b0)
    store_b(b0);
    lwriteX(1);                      // b1 -> slab e1

    // ---- batch b1 ----
    compute_half(0);
    compute_half(1);
    store_b(b1);
}

extern "C" void kernel_launch(void* const* d_in, const int* in_sizes, int n_in,
                              void* d_out, int out_size, void* d_ws, size_t ws_size,
                              hipStream_t stream)
{
    const float* x = (const float*)d_in[0];           // (8,128,128,128) fp32
    const float* w = (const float*)d_in[1];           // (256,32,128,9) fp32
    float* out = (float*)d_out;                       // (8,256,64,128) fp32
    unsigned short* wb = (unsigned short*)d_ws;       // 256*36864 bf16 = 18.9 MB

    (void)hipFuncSetAttribute((const void*)lconv_mfma,
                              hipFuncAttributeMaxDynamicSharedMemorySize, 160768);

    hipLaunchKernelGGL(prep_w, dim3(256), dim3(256), 0, stream, w, wb);
    hipLaunchKernelGGL(lconv_mfma, dim3(256), dim3(256), 160768, stream, x, wb, out);
}